// Round 3
// baseline (174.357 us; speedup 1.0000x reference)
//
#include <hip/hip_runtime.h>

// SSIM (7x7 uniform window) over B=64, C=1, H=W=384 fp32 images.
// out = mean over interior 378x378 crop of all 64 images (scalar).
//
// Kernel 1: max(gt) -> ws_max (monotone-encoded uint)
// Kernel 2: fused separable box-filter SSIM. Full-row blocks (192 thr),
//           2 output cols/thread (float2), register vertical ring,
//           double accumulation + last-block finalize -> d_out[0].

#define PADW 3
#define BT 192            // threads per block (3 waves); 189 compute 2 cols each
#define BAND 15           // output rows per block
#define NIN 21            // input rows per block (3 chunks of 7)
#define NCHUNK 3

constexpr int B_ = 64, H_ = 384, W_ = 384;
constexpr int W2 = W_ / 2;                                // row length in float2
constexpr int OUTD = W_ - 2 * PADW;                       // 378
constexpr int NBANDS = (OUTD + BAND - 1) / BAND;          // 26
constexpr int TOTAL_BLOCKS = NBANDS * B_;                 // 1664
constexpr double NPIX = (double)B_ * OUTD * OUTD;         // 9,144,576

__device__ __forceinline__ unsigned enc_f(float f) {
    unsigned u = __float_as_uint(f);
    return (u & 0x80000000u) ? ~u : (u | 0x80000000u);
}
__device__ __forceinline__ float dec_f(unsigned e) {
    return __uint_as_float((e & 0x80000000u) ? (e & 0x7fffffffu) : ~e);
}

__device__ __forceinline__ float2 f2add(float2 a, float2 b) { return make_float2(a.x + b.x, a.y + b.y); }
__device__ __forceinline__ float2 f2sub(float2 a, float2 b) { return make_float2(a.x - b.x, a.y - b.y); }

__global__ void __launch_bounds__(256)
max_kernel(const float4* __restrict__ g4, unsigned* ws_max, int n4) {
    int tid = blockIdx.x * blockDim.x + threadIdx.x;
    int stride = gridDim.x * blockDim.x;
    float m = -3.402823466e38f;
    for (int i = tid; i < n4; i += stride) {
        float4 v = g4[i];
        m = fmaxf(m, fmaxf(fmaxf(v.x, v.y), fmaxf(v.z, v.w)));
    }
#pragma unroll
    for (int off = 32; off > 0; off >>= 1)
        m = fmaxf(m, __shfl_down(m, off));
    __shared__ float sm[4];
    if ((threadIdx.x & 63) == 0) sm[threadIdx.x >> 6] = m;
    __syncthreads();
    if (threadIdx.x == 0) {
        float mm = fmaxf(fmaxf(sm[0], sm[1]), fmaxf(sm[2], sm[3]));
        atomicMax(ws_max, enc_f(mm));
    }
}

__device__ __forceinline__ float ssim_px(float sx, float sy, float sxx, float syy, float sxy,
                                         float C1, float C2) {
    const float inv49 = 1.0f / 49.0f;
    const float covn  = 49.0f / 48.0f;
    float ux  = sx * inv49, uy = sy * inv49;
    float uxx = sxx * inv49 - ux * ux;
    float uyy = syy * inv49 - uy * uy;
    float uxy = sxy * inv49 - ux * uy;
    float vvx = covn * uxx, vvy = covn * uyy, vvxy = covn * uxy;
    float num = (2.0f * ux * uy + C1) * (2.0f * vvxy + C2);
    float den = (ux * ux + uy * uy + C1) * (vvx + vvy + C2);
    return num / den;
}

__global__ void __launch_bounds__(BT)
ssim_kernel(const float* __restrict__ gt, const float* __restrict__ pred,
            const unsigned* __restrict__ ws_max, double* ws_sum, unsigned* ws_cnt,
            float* __restrict__ out) {
    const int t    = threadIdx.x;
    const int band = blockIdx.x;   // 0..NBANDS-1
    const int b    = blockIdx.y;   // 0..63 images

    const float dr = dec_f(*ws_max);
    const float C1 = (0.01f * dr) * (0.01f * dr);
    const float C2 = (0.03f * dr) * (0.03f * dr);

    const int  row0   = band * BAND;
    const bool active = (t < 189);            // thread t -> output cols 3+2t, 4+2t

    // full rows staged as float2; +4 slop so t+3 reads by tail threads stay in-bounds
    __shared__ float2 sg[7][BT + 4];
    __shared__ float2 sp[7][BT + 4];
    __shared__ double sred[3];

    // vertical ring of horizontal 7-tap sums (x2 columns packed in float2)
    float2 rx[7], ry[7], rxx[7], ryy[7], rxy[7];
#pragma unroll
    for (int j = 0; j < 7; ++j) {
        rx[j] = make_float2(0.f, 0.f); ry[j] = rx[j];
        rxx[j] = rx[j]; ryy[j] = rx[j]; rxy[j] = rx[j];
    }
    float2 vx = make_float2(0.f, 0.f), vy = vx, vxx = vx, vyy = vx, vxy = vx;
    double acc = 0.0;

    const float2* gbase = (const float2*)(gt   + (size_t)b * H_ * W_);
    const float2* pbase = (const float2*)(pred + (size_t)b * H_ * W_);

    for (int c = 0; c < NCHUNK; ++c) {
        __syncthreads();   // protect previous chunk's sg/sp reads
#pragma unroll
        for (int j = 0; j < 7; ++j) {
            const int ir = min(row0 + c * 7 + j, H_ - 1);
            sg[j][t] = gbase[(size_t)ir * W2 + t];
            sp[j][t] = pbase[(size_t)ir * W2 + t];
        }
        __syncthreads();

#pragma unroll
        for (int j = 0; j < 7; ++j) {
            // 8 taps (4 float2) covering both columns' 7-tap windows
            float2 d0 = sg[j][t], d1 = sg[j][t + 1], d2 = sg[j][t + 2], d3 = sg[j][t + 3];
            float2 e0 = sp[j][t], e1 = sp[j][t + 1], e2 = sp[j][t + 2], e3 = sp[j][t + 3];

            float hx0 = d0.x + d0.y + d1.x + d1.y + d2.x + d2.y + d3.x;
            float hy0 = e0.x + e0.y + e1.x + e1.y + e2.x + e2.y + e3.x;
            float hxx0 = fmaf(d0.x, d0.x, fmaf(d0.y, d0.y, fmaf(d1.x, d1.x,
                         fmaf(d1.y, d1.y, fmaf(d2.x, d2.x, fmaf(d2.y, d2.y, d3.x * d3.x))))));
            float hyy0 = fmaf(e0.x, e0.x, fmaf(e0.y, e0.y, fmaf(e1.x, e1.x,
                         fmaf(e1.y, e1.y, fmaf(e2.x, e2.x, fmaf(e2.y, e2.y, e3.x * e3.x))))));
            float hxy0 = fmaf(d0.x, e0.x, fmaf(d0.y, e0.y, fmaf(d1.x, e1.x,
                         fmaf(d1.y, e1.y, fmaf(d2.x, e2.x, fmaf(d2.y, e2.y, d3.x * e3.x))))));

            // horizontal slide for the second column: -tap0 +tap7
            float2 h_x  = make_float2(hx0,  hx0  - d0.x        + d3.y);
            float2 h_y  = make_float2(hy0,  hy0  - e0.x        + e3.y);
            float2 h_xx = make_float2(hxx0, hxx0 - d0.x * d0.x + d3.y * d3.y);
            float2 h_yy = make_float2(hyy0, hyy0 - e0.x * e0.x + e3.y * e3.y);
            float2 h_xy = make_float2(hxy0, hxy0 - d0.x * e0.x + d3.y * e3.y);

            // vertical sliding window: evict slot j, insert new row
            vx  = f2add(vx,  f2sub(h_x,  rx[j]));  rx[j]  = h_x;
            vy  = f2add(vy,  f2sub(h_y,  ry[j]));  ry[j]  = h_y;
            vxx = f2add(vxx, f2sub(h_xx, rxx[j])); rxx[j] = h_xx;
            vyy = f2add(vyy, f2sub(h_yy, ryy[j])); ryy[j] = h_yy;
            vxy = f2add(vxy, f2sub(h_xy, rxy[j])); rxy[j] = h_xy;

            const int i = c * 7 + j;
            if (i >= 6) {
                const int orow = row0 + i - 6;
                if (active && orow < OUTD) {
                    acc += (double)ssim_px(vx.x, vy.x, vxx.x, vyy.x, vxy.x, C1, C2);
                    acc += (double)ssim_px(vx.y, vy.y, vxx.y, vyy.y, vxy.y, C1, C2);
                }
            }
        }
    }

    // block reduction (double) -> one f64 atomic per block; last block finalizes
#pragma unroll
    for (int off = 32; off > 0; off >>= 1)
        acc += __shfl_down(acc, off);
    if ((t & 63) == 0) sred[t >> 6] = acc;
    __syncthreads();
    if (t == 0) {
        atomicAdd(ws_sum, sred[0] + sred[1] + sred[2]);
        __threadfence();
        unsigned prev = atomicAdd(ws_cnt, 1u);
        if (prev == (unsigned)(TOTAL_BLOCKS - 1)) {
            double tot = atomicAdd(ws_sum, 0.0);   // coherent read-back
            out[0] = (float)(tot / NPIX);
        }
    }
}

extern "C" void kernel_launch(void* const* d_in, const int* in_sizes, int n_in,
                              void* d_out, int out_size, void* d_ws, size_t ws_size,
                              hipStream_t stream) {
    const float* gt   = (const float*)d_in[0];
    const float* pred = (const float*)d_in[1];
    // d_in[2] is the uniform 1/49 window -> constant-folded into the kernel.
    float* out = (float*)d_out;

    unsigned* ws_max = (unsigned*)d_ws;                    // offset 0
    unsigned* ws_cnt = (unsigned*)((char*)d_ws + 4);       // offset 4
    double*   ws_sum = (double*)((char*)d_ws + 8);         // offset 8

    hipMemsetAsync(d_ws, 0, 16, stream);

    const int n4 = B_ * H_ * W_ / 4;  // 2,359,296 float4s
    max_kernel<<<1024, 256, 0, stream>>>((const float4*)gt, ws_max, n4);

    dim3 grid(NBANDS, B_);            // row bands x images
    ssim_kernel<<<grid, BT, 0, stream>>>(gt, pred, ws_max, ws_sum, ws_cnt, out);
}